// Round 7
// baseline (382.276 us; speedup 1.0000x reference)
//
#include <hip/hip_runtime.h>
#include <stdint.h>

// ---------------- problem constants (from reference) ----------------
#define DIN   4096
#define DOUT  4096
#define RANK  16
#define MTOT  8192            // 4 * 2048
#define LSCALE 2.0f           // alpha/rank = 32/16

typedef unsigned short u16;
typedef __bf16 bf16x8 __attribute__((ext_vector_type(8)));
typedef float  f32x4  __attribute__((ext_vector_type(4)));
typedef u16    u16x8  __attribute__((ext_vector_type(8)));

__device__ __forceinline__ u16 f2bf(float f) {
    uint32_t u = __builtin_bit_cast(uint32_t, f);
    u = (u + 0x7FFFu + ((u >> 16) & 1u)) >> 16;   // RNE
    return (u16)u;
}

__device__ __forceinline__ u16x8 pack8(f32x4 a, f32x4 b) {
    u16x8 o;
    o[0] = f2bf(a[0]); o[1] = f2bf(a[1]); o[2] = f2bf(a[2]); o[3] = f2bf(a[3]);
    o[4] = f2bf(b[0]); o[5] = f2bf(b[1]); o[6] = f2bf(b[2]); o[7] = f2bf(b[3]);
    return o;
}

#define GLDS16(g, l) __builtin_amdgcn_global_load_lds( \
    (const __attribute__((address_space(1))) void*)(g), \
    (__attribute__((address_space(3))) void*)(l), 16, 0, 0)

// ---------------- fused prep: x->bf16  and  W_eff = W + scale*B@A -> bf16 ----
#define CONV_BLOCKS 16384   // MTOT*DIN/8/256
#define WEFF_BLOCKS 8192    // DOUT*DIN/8/256
__global__ __launch_bounds__(256) void k_prep(const float* __restrict__ x,
                                              u16* __restrict__ xb,
                                              const float* __restrict__ W,
                                              const float* __restrict__ A,
                                              const float* __restrict__ B,
                                              u16* __restrict__ wb) {
    const int b = blockIdx.x;
    if (b < CONV_BLOCKS) {
        long i = ((long)b * 256 + threadIdx.x) * 8;
        f32x4 a = *(const f32x4*)(x + i);
        f32x4 c = *(const f32x4*)(x + i + 4);
        *(u16x8*)(xb + i) = pack8(a, c);
    } else {
        long t = (long)(b - CONV_BLOCKS) * 256 + threadIdx.x;
        long i = t * 8;
        int o = (int)(i >> 12);        // / DIN
        int d = (int)(i & (DIN - 1));
        float sB[RANK];
#pragma unroll
        for (int r = 0; r < RANK; ++r) sB[r] = B[o * RANK + r] * LSCALE;
        f32x4 w0 = *(const f32x4*)(W + i);
        f32x4 w1 = *(const f32x4*)(W + i + 4);
#pragma unroll
        for (int r = 0; r < RANK; ++r) {
            f32x4 a0 = *(const f32x4*)(A + (long)r * DIN + d);
            f32x4 a1 = *(const f32x4*)(A + (long)r * DIN + d + 4);
            w0 += a0 * sB[r];
            w1 += a1 * sB[r];
        }
        *(u16x8*)(wb + i) = pack8(w0, w1);
    }
}

// ---------------- main GEMM: out = xb @ wb^T + bias ----------------
// 256x128 block, 4 waves (2Mx2N, wave 128x64), BK=64. LDS 64 KiB:
//   A single-buffered [256][64] + B double-buffered 2x[128][64]
// -> 2 independent blocks per CU (cross-block TLP overlaps LDS with MFMA;
//    barriers are per-workgroup so no CU-wide lockstep).
// Per K-tile: only TWO barriers (end-P3 guards A-overwrite; tile-end after
// vmcnt(0) guards next-tile reads). n-first quad order caps live frags at 16.
//   P1: read af03+bf01(B[p]); stage B(t+1)->B[p^1]; Q1 = m0-3 x n0-1
//   P2: read bf23;                                  Q2 = m0-3 x n2-3
//   P3: read af47;                                  Q3 = m4-7 x n0-1; BAR
//   P4: stage A(t+1);                               Q4 = m4-7 x n2-3; vmcnt0; BAR
#define BM 256
#define BN 128
#define BK 64
#define NT (DIN / BK)          // 64 K-tiles

#define MFMA16(d, a, b) d = __builtin_amdgcn_mfma_f32_16x16x32_bf16(a, b, d, 0, 0, 0)
#define ABAR()   asm volatile("s_barrier" ::: "memory")
#define VM0()    asm volatile("s_waitcnt vmcnt(0)" ::: "memory")
#define PRIO1()  __builtin_amdgcn_s_setprio(1)
#define PRIO0()  __builtin_amdgcn_s_setprio(0)

// 16 MFMAs, kk-outer (8 independent accs between dependent reuses)
#define QUADK(mo, no, AF, BF) \
    _Pragma("unroll") \
    for (int kk = 0; kk < 2; ++kk) { \
        _Pragma("unroll") \
        for (int m = 0; m < 4; ++m) { \
            _Pragma("unroll") \
            for (int n = 0; n < 2; ++n) { \
                MFMA16(acc[(mo)+m][(no)+n], AF[m][kk], BF[n][kk]); \
            } \
        } \
    }

__global__ __launch_bounds__(256, 2) void k_gemm_ws(const u16* __restrict__ xb,
                                                    const u16* __restrict__ wb,
                                                    const float* __restrict__ bias,
                                                    float* __restrict__ out) {
    constexpr int K = DIN, N = DOUT;
    // A: [0,16384) u16 (32 KiB). B0: [16384,24576). B1: [24576,32768).
    __shared__ alignas(16) u16 lds[32768];   // 64 KiB

    // T1: bijective XCD swizzle (gridDim.x = 1024, divisible by 8)
    const int nchunk = gridDim.x >> 3;          // 128
    const int bid = blockIdx.x;
    const int wg  = (bid & 7) * nchunk + (bid >> 3);
    const int bm  = (wg & 31) * BM;             // 32 m-tiles
    const int bn  = (wg >> 5) * BN;             // 32 n-tiles

    const int tid  = threadIdx.x;               // 0..255
    const int lane = tid & 63;
    const int wid  = tid >> 6;                  // 0..3
    const int wr   = wid >> 1;                  // 0..1 -> rows wr*128..+127
    const int wc   = wid & 1;                   // 0..1 -> cols wc*64..+63
    const int lrow = lane & 15;
    const int kgrp = lane >> 4;                 // 0..3

    // ---- staging geometry (pre-swizzled global source, linear LDS dest) ----
    const int srow = tid >> 3;                  // 0..31
    const int sgl  = (tid & 7) ^ (srow & 7);
    const u16* const aSrcB = xb + (long)(bm + srow) * K + sgl * 8;
    const u16* const bSrcB = wb + (long)(bn + srow) * K + sgl * 8;

    // chunk c covers rows 32c..32c+31 (A: c=0..7, B: c=0..3)
#define STAGE_A(c, kt) GLDS16(aSrcB + (long)(32*(c))*K + (kt)*BK, \
                              lds + (c)*2048 + tid*8)
#define STAGE_B(c, q, kt) GLDS16(bSrcB + (long)(32*(c))*K + (kt)*BK, \
                                 lds + 16384 + (q)*8192 + (c)*2048 + tid*8)

    // ---- fragment-read geometry (swizzled) ----
    const int go0 = (kgrp ^ (lrow & 7)) * 8;    // kk=0 granule (u16 units)
    const int go1 = go0 ^ 32;                   // kk=1 (granule ^ 4)
    const int arow = (wr*128 + lrow) * 64;      // A row base (u16)
    const int brow = (wc*64  + lrow) * 64;      // B row base within a B buf

    f32x4 acc[8][4];
#pragma unroll
    for (int m = 0; m < 8; ++m)
#pragma unroll
        for (int n = 0; n < 4; ++n) acc[m][n] = (f32x4){0.f, 0.f, 0.f, 0.f};

    bf16x8 af03[4][2], af47[4][2], bf01[2][2], bf23[2][2];

    // ---- prologue: A(0), B(0)->B0, B(1)->B1; full drain ----
#pragma unroll
    for (int c = 0; c < 8; ++c) STAGE_A(c, 0);
#pragma unroll
    for (int c = 0; c < 4; ++c) STAGE_B(c, 0, 0);
#pragma unroll
    for (int c = 0; c < 4; ++c) STAGE_B(c, 1, 1);
    VM0();
    __syncthreads();

    for (int t = 0; t < NT; ++t) {
        const int p = t & 1;
        const int ktn = (t + 1) & (NT - 1);     // wrap: last-iter stage unused
        const u16* const pB = lds + 16384 + p * 8192;

        // ---- P1: read af03 + bf01; stage B(t+1)->B[p^1]; Q1 ----
#pragma unroll
        for (int mf = 0; mf < 4; ++mf) {
            const u16* b = lds + arow + mf * 1024;
            af03[mf][0] = *(const bf16x8*)(b + go0);
            af03[mf][1] = *(const bf16x8*)(b + go1);
        }
#pragma unroll
        for (int nf = 0; nf < 2; ++nf) {
            const u16* b = pB + brow + nf * 1024;
            bf01[nf][0] = *(const bf16x8*)(b + go0);
            bf01[nf][1] = *(const bf16x8*)(b + go1);
        }
#pragma unroll
        for (int c = 0; c < 4; ++c) STAGE_B(c, p ^ 1, ktn);
        PRIO1(); QUADK(0, 0, af03, bf01); PRIO0();

        // ---- P2: read bf23; Q2 ----
#pragma unroll
        for (int nf = 0; nf < 2; ++nf) {
            const u16* b = pB + brow + (nf + 2) * 1024;
            bf23[nf][0] = *(const bf16x8*)(b + go0);
            bf23[nf][1] = *(const bf16x8*)(b + go1);
        }
        PRIO1(); QUADK(0, 2, af03, bf23); PRIO0();

        // ---- P3: read af47; Q3; barrier (A region now fully consumed) ----
#pragma unroll
        for (int mf = 0; mf < 4; ++mf) {
            const u16* b = lds + arow + (mf + 4) * 1024;
            af47[mf][0] = *(const bf16x8*)(b + go0);
            af47[mf][1] = *(const bf16x8*)(b + go1);
        }
        PRIO1(); QUADK(4, 0, af47, bf01); PRIO0();
        ABAR();

        // ---- P4: stage A(t+1); Q4; drain; tile-end barrier ----
#pragma unroll
        for (int c = 0; c < 8; ++c) STAGE_A(c, ktn);
        PRIO1(); QUADK(4, 2, af47, bf23); PRIO0();
        VM0();
        ABAR();
    }

    // ---- epilogue: + bias, store f32 ----
    const int orow = bm + wr*128 + kgrp*4;
    const int ocol = bn + wc*64 + lrow;
#pragma unroll
    for (int n = 0; n < 4; ++n) {
        const int col = ocol + n*16;
        const float bj = bias[col];
#pragma unroll
        for (int m = 0; m < 8; ++m) {
            const int row = orow + m*16;
#pragma unroll
            for (int r = 0; r < 4; ++r)
                out[(long)(row + r) * N + col] = acc[m][n][r] + bj;
        }
    }
}

// ---------------- fallback: T = scale * x @ A^T  (one wave per row) ----------------
__global__ __launch_bounds__(64) void k_lora_T(const float* __restrict__ x,
                                               const float* __restrict__ A,
                                               float* __restrict__ T) {
    const int m = blockIdx.x;
    const int lane = threadIdx.x;
    const float* xr = x + (long)m * DIN;
    float acc[RANK];
#pragma unroll
    for (int r = 0; r < RANK; ++r) acc[r] = 0.f;
    for (int k = lane * 4; k < DIN; k += 64 * 4) {
        f32x4 xv = *(const f32x4*)(xr + k);
#pragma unroll
        for (int r = 0; r < RANK; ++r) {
            f32x4 av = *(const f32x4*)(A + (long)r * DIN + k);
            acc[r] += xv[0] * av[0] + xv[1] * av[1] + xv[2] * av[2] + xv[3] * av[3];
        }
    }
#pragma unroll
    for (int r = 0; r < RANK; ++r)
        for (int off = 32; off > 0; off >>= 1) acc[r] += __shfl_down(acc[r], off);
    if (lane == 0) {
#pragma unroll
        for (int r = 0; r < RANK; ++r) T[(long)m * RANK + r] = acc[r] * LSCALE;
    }
}

// ---------------- fallback GEMM: f32 sources, reg-staged conversion ----------------
__global__ __launch_bounds__(256) void k_gemm_nows(const float* __restrict__ x,
                                                   const float* __restrict__ W,
                                                   const float* __restrict__ bias,
                                                   const float* __restrict__ T,
                                                   const float* __restrict__ lB,
                                                   float* __restrict__ out) {
    constexpr int FBM = 128, FBN = 128, FBK = 32, K = DIN, N = DOUT;
    __shared__ __align__(16) u16 As[FBM * FBK];
    __shared__ __align__(16) u16 Bs[FBN * FBK];

    const int tid = threadIdx.x;
    const int bm = blockIdx.y * FBM;
    const int bn = blockIdx.x * FBN;
    const int lane = tid & 63;
    const int wid  = tid >> 6;
    const int wr = wid >> 1, wc = wid & 1;
    const int lrow = lane & 15;
    const int kgrp = lane >> 4;

    const int c0 = tid, c1 = tid + 256;
    const float* aS0 = x + (long)(bm + (c0 >> 2)) * K + (c0 & 3) * 8;
    const float* aS1 = x + (long)(bm + (c1 >> 2)) * K + (c1 & 3) * 8;
    const float* bS0 = W + (long)(bn + (c0 >> 2)) * K + (c0 & 3) * 8;
    const float* bS1 = W + (long)(bn + (c1 >> 2)) * K + (c1 & 3) * 8;
    u16* aD0 = As + c0 * 8;  u16* aD1 = As + c1 * 8;
    u16* bD0 = Bs + c0 * 8;  u16* bD1 = Bs + c1 * 8;

    const u16* aR = As + (wr * 64 + lrow) * FBK + kgrp * 8;
    const u16* bR = Bs + (wc * 64 + lrow) * FBK + kgrp * 8;

    f32x4 acc[4][4];
#pragma unroll
    for (int i = 0; i < 4; ++i)
#pragma unroll
        for (int j = 0; j < 4; ++j) acc[i][j] = (f32x4){0.f, 0.f, 0.f, 0.f};

    for (int k0 = 0; k0 < K; k0 += FBK) {
        f32x4 a00 = *(const f32x4*)aS0, a01 = *(const f32x4*)(aS0 + 4);
        f32x4 a10 = *(const f32x4*)aS1, a11 = *(const f32x4*)(aS1 + 4);
        f32x4 b00 = *(const f32x4*)bS0, b01 = *(const f32x4*)(bS0 + 4);
        f32x4 b10 = *(const f32x4*)bS1, b11 = *(const f32x4*)(bS1 + 4);
        aS0 += FBK; aS1 += FBK; bS0 += FBK; bS1 += FBK;
        if (k0) __syncthreads();
        *(u16x8*)aD0 = pack8(a00, a01);
        *(u16x8*)aD1 = pack8(a10, a11);
        *(u16x8*)bD0 = pack8(b00, b01);
        *(u16x8*)bD1 = pack8(b10, b11);
        __syncthreads();

        bf16x8 af[4], bf[4];
#pragma unroll
        for (int i = 0; i < 4; ++i) af[i] = *(const bf16x8*)(aR + i * 16 * FBK);
#pragma unroll
        for (int j = 0; j < 4; ++j) bf[j] = *(const bf16x8*)(bR + j * 16 * FBK);
#pragma unroll
        for (int i = 0; i < 4; ++i)
#pragma unroll
            for (int j = 0; j < 4; ++j)
                acc[i][j] = __builtin_amdgcn_mfma_f32_16x16x32_bf16(af[i], bf[j], acc[i][j], 0, 0, 0);
    }

#pragma unroll
    for (int j = 0; j < 4; ++j) {
        const int col = bn + wc * 64 + j * 16 + lrow;
        const float bj = bias[col];
        float bl[RANK];
#pragma unroll
        for (int q = 0; q < RANK; ++q) bl[q] = lB[(long)col * RANK + q];
#pragma unroll
        for (int i = 0; i < 4; ++i) {
            const int row0 = bm + wr * 64 + i * 16 + kgrp * 4;
#pragma unroll
            for (int r = 0; r < 4; ++r) {
                const int row = row0 + r;
                const float* Trow = T + (long)row * RANK;
                float s = bj;
#pragma unroll
                for (int q = 0; q < RANK; ++q) s += Trow[q] * bl[q];
                out[(long)row * N + col] = acc[i][j][r] + s;
            }
        }
    }
}

extern "C" void kernel_launch(void* const* d_in, const int* in_sizes, int n_in,
                              void* d_out, int out_size, void* d_ws, size_t ws_size,
                              hipStream_t stream) {
    const float* x    = (const float*)d_in[0];
    const float* W    = (const float*)d_in[1];
    const float* bias = (const float*)d_in[2];
    const float* lA   = (const float*)d_in[3];
    const float* lB   = (const float*)d_in[4];
    float* out = (float*)d_out;

    const size_t xb_bytes = (size_t)MTOT * DIN * sizeof(u16);   // 64 MiB
    const size_t wb_bytes = (size_t)DOUT * DIN * sizeof(u16);   // 32 MiB

    if (ws_size >= xb_bytes + wb_bytes) {
        u16* xb = (u16*)d_ws;
        u16* wb = (u16*)((char*)d_ws + xb_bytes);
        k_prep   <<<CONV_BLOCKS + WEFF_BLOCKS, 256, 0, stream>>>(x, xb, W, lA, lB, wb);
        k_gemm_ws<<<(MTOT / BM) * (DOUT / BN), 256, 0, stream>>>(xb, wb, bias, out);
    } else {
        float* T = (float*)d_ws;   // 512 KiB
        k_lora_T   <<<MTOT, 64, 0, stream>>>(x, lA, T);
        k_gemm_nows<<<dim3(DOUT / 128, MTOT / 128), 256, 0, stream>>>(x, W, bias, T, lB, out);
    }
}

// Round 8
// 333.149 us; speedup vs baseline: 1.1475x; 1.1475x over previous
//
#include <hip/hip_runtime.h>
#include <stdint.h>

// ---------------- problem constants (from reference) ----------------
#define DIN   4096
#define DOUT  4096
#define RANK  16
#define MTOT  8192            // 4 * 2048
#define LSCALE 2.0f           // alpha/rank = 32/16

typedef unsigned short u16;
typedef __bf16 bf16x8 __attribute__((ext_vector_type(8)));
typedef float  f32x4  __attribute__((ext_vector_type(4)));
typedef u16    u16x8  __attribute__((ext_vector_type(8)));

__device__ __forceinline__ u16 f2bf(float f) {
    uint32_t u = __builtin_bit_cast(uint32_t, f);
    u = (u + 0x7FFFu + ((u >> 16) & 1u)) >> 16;   // RNE
    return (u16)u;
}

__device__ __forceinline__ u16x8 pack8(f32x4 a, f32x4 b) {
    u16x8 o;
    o[0] = f2bf(a[0]); o[1] = f2bf(a[1]); o[2] = f2bf(a[2]); o[3] = f2bf(a[3]);
    o[4] = f2bf(b[0]); o[5] = f2bf(b[1]); o[6] = f2bf(b[2]); o[7] = f2bf(b[3]);
    return o;
}

#define GLDS16(g, l) __builtin_amdgcn_global_load_lds( \
    (const __attribute__((address_space(1))) void*)(g), \
    (__attribute__((address_space(3))) void*)(l), 16, 0, 0)

// ---------------- pass 1a: x (f32) -> xb (bf16) ----------------
__global__ __launch_bounds__(256) void k_convert_x(const float* __restrict__ x,
                                                   u16* __restrict__ xb) {
    long i = ((long)blockIdx.x * 256 + threadIdx.x) * 8;
    f32x4 a = *(const f32x4*)(x + i);
    f32x4 b = *(const f32x4*)(x + i + 4);
    *(u16x8*)(xb + i) = pack8(a, b);
}

// ---------------- pass 1b: W_eff = W + scale * B @ A  (bf16) ----------------
__global__ __launch_bounds__(256) void k_build_weff(const float* __restrict__ W,
                                                    const float* __restrict__ A,
                                                    const float* __restrict__ B,
                                                    u16* __restrict__ wb) {
    long t = (long)blockIdx.x * 256 + threadIdx.x;
    long i = t * 8;
    int o = (int)(i >> 12);        // / DIN
    int d = (int)(i & (DIN - 1));
    float sB[RANK];
#pragma unroll
    for (int r = 0; r < RANK; ++r) sB[r] = B[o * RANK + r] * LSCALE;
    f32x4 w0 = *(const f32x4*)(W + i);
    f32x4 w1 = *(const f32x4*)(W + i + 4);
#pragma unroll
    for (int r = 0; r < RANK; ++r) {
        f32x4 a0 = *(const f32x4*)(A + (long)r * DIN + d);
        f32x4 a1 = *(const f32x4*)(A + (long)r * DIN + d + 4);
        w0 += a0 * sB[r];
        w1 += a1 * sB[r];
    }
    *(u16x8*)(wb + i) = pack8(w0, w1);
}

// ---------------- main GEMM: out = xb @ wb^T + bias ----------------
// m201-faithful 8-phase: 256x256, BK=64, 8 waves (2Mx4N, wave 128x64).
// Per K-tile 4 phases, reads 8/4/8/4 (bfLo of tile t+1 read-ahead at P4(t)
// post-gate), ONE counted gate vmcnt(4)/tile, NO sched_barrier, NO explicit
// lgkmcnt (compiler emits fine-grained lgkm waits for the C++-level ds reads).
//   P1: stage A.lo(t+1); read afL(8);  BAR; Q1=afL*bfLo;  BAR
//   P2: stage A.hi(t+1); read bfHi(4); BAR; Q2=afL*bfHi;  BAR
//   P3: stage B.lo(t+2); read afH(8);  BAR; Q3=afH*bfLo;  BAR
//   P4: stage B.hi(t+2); GATE vmcnt(4); read bfLo(t+1)(4); BAR; Q4=afH*bfHi; BAR
// FIFO at P4(t) gate: outstanding = {B.lo(t+1),B.hi(t+1),A.lo(t+1),A.hi(t+1),
// B.lo(t+2),B.hi(t+2)} = 12; vmcnt(4) retires all of t+1 (covers 2-4 phases),
// keeps B(t+2) in flight. vmcnt never 0 in loop.
#define BM 256
#define BN 256
#define BK 64
#define NT (DIN / BK)          // 64 K-tiles

#define MFMA16(d, a, b) d = __builtin_amdgcn_mfma_f32_16x16x32_bf16(a, b, d, 0, 0, 0)
#define RBAR()   __builtin_amdgcn_s_barrier()
#define GATE4()  asm volatile("s_waitcnt vmcnt(4)" ::: "memory")
#define PRIO1()  __builtin_amdgcn_s_setprio(1)
#define PRIO0()  __builtin_amdgcn_s_setprio(0)

// 16 MFMAs, kk-outer (8 independent accs between dependent reuses)
#define QUADK(mo, no, AF, BF) \
    _Pragma("unroll") \
    for (int kk = 0; kk < 2; ++kk) { \
        _Pragma("unroll") \
        for (int m = 0; m < 4; ++m) { \
            _Pragma("unroll") \
            for (int n = 0; n < 2; ++n) { \
                MFMA16(acc[(mo)+m][(no)+n], AF[m][kk], BF[n][kk]); \
            } \
        } \
    }

__global__ __launch_bounds__(512, 2) void k_gemm_ws(const u16* __restrict__ xb,
                                                    const u16* __restrict__ wb,
                                                    const float* __restrict__ bias,
                                                    float* __restrict__ out) {
    constexpr int K = DIN, N = DOUT;
    __shared__ alignas(16) u16 lds[65536];   // A0@0 A1@16384 B0@32768 B1@49152 (u16)

    // T1: bijective XCD swizzle (gridDim.x = 512, divisible by 8)
    const int nchunk = gridDim.x >> 3;
    const int bid = blockIdx.x;
    const int wg  = (bid & 7) * nchunk + (bid >> 3);
    const int bm  = (wg & 31) * BM;
    const int bn  = (wg >> 5) * BN;

    const int tid  = threadIdx.x;
    const int lane = tid & 63;
    const int wid  = tid >> 6;         // 0..7
    const int wr   = wid >> 2;         // 0..1 -> rows wr*128..+127
    const int wc   = wid & 3;          // 0..3 -> cols wc*64..+63
    const int lrow = lane & 15;
    const int kgrp = lane >> 4;        // 0..3

    // ---- staging geometry (T2: pre-swizzled global source, linear LDS dest) ----
    const int srow = tid >> 3;                       // 0..63
    const int sgl  = (tid & 7) ^ (srow & 7);
    const u16* const aSrcB = xb + (long)(bm + srow) * K + sgl * 8;
    const u16* const bSrcB = wb + (long)(bn + srow) * K + sgl * 8;

    // chunk c = tile rows 64c..64c+63. lo = c0,c1; hi = c2,c3.
#define STAGE_A(c, buf, kt) GLDS16(aSrcB + (long)(64*(c))*K + (kt)*BK, \
                                   lds + (buf)*16384 + (c)*4096 + tid*8)
#define STAGE_B(c, buf, kt) GLDS16(bSrcB + (long)(64*(c))*K + (kt)*BK, \
                                   lds + 32768 + (buf)*16384 + (c)*4096 + tid*8)

    // ---- fragment-read geometry (swizzled) ----
    const int go0 = (kgrp ^ (lrow & 7)) * 8;   // kk=0 granule (u16 units)
    const int go1 = go0 ^ 32;                  // kk=1 (granule ^ 4)
    const int arow = (wr*128 + lrow) * 64;     // wave A base row offset
    const int brow = (wc*64  + lrow) * 64;     // wave B base row offset

    f32x4 acc[8][4];
#pragma unroll
    for (int m = 0; m < 8; ++m)
#pragma unroll
        for (int n = 0; n < 4; ++n) acc[m][n] = (f32x4){0.f, 0.f, 0.f, 0.f};

    bf16x8 afL[4][2], afH[4][2], bfLo[2][2], bfHi[2][2];

    // ---- prologue: tile0 -> buf0, B(1) -> buf1; counted gate; read bfLo(0) ----
    STAGE_A(0, 0, 0); STAGE_A(1, 0, 0);
    STAGE_A(2, 0, 0); STAGE_A(3, 0, 0);
    STAGE_B(0, 0, 0); STAGE_B(1, 0, 0);
    STAGE_B(2, 0, 0); STAGE_B(3, 0, 0);
    STAGE_B(0, 1, 1); STAGE_B(1, 1, 1);
    STAGE_B(2, 1, 1); STAGE_B(3, 1, 1);
    GATE4();                       // retires tile0's 8; keeps B(1) in flight
    __syncthreads();
#pragma unroll
    for (int nf = 0; nf < 2; ++nf) {
        const u16* b = lds + 32768 + brow + nf * 1024;
        bfLo[nf][0] = *(const bf16x8*)(b + go0);
        bfLo[nf][1] = *(const bf16x8*)(b + go1);
    }

    for (int t = 0; t < NT; ++t) {
        const int cur = t & 1, nxt = cur ^ 1;
        const int kt1 = (t + 1) & (NT - 1);
        const int kt2 = (t + 2) & (NT - 1);
        const u16* const cA = lds + cur * 16384;
        const u16* const cB = lds + 32768 + cur * 16384;
        const u16* const nB = lds + 32768 + nxt * 16384;

        // ===== P1: stage A.lo(t+1); read afL(8); Q1 = afL x bfLo =====
        STAGE_A(0, nxt, kt1); STAGE_A(1, nxt, kt1);
#pragma unroll
        for (int mf = 0; mf < 4; ++mf) {
            const u16* b = cA + arow + mf * 1024;
            afL[mf][0] = *(const bf16x8*)(b + go0);
            afL[mf][1] = *(const bf16x8*)(b + go1);
        }
        RBAR();
        PRIO1(); QUADK(0, 0, afL, bfLo); PRIO0();
        RBAR();

        // ===== P2: stage A.hi(t+1); read bfHi(4); Q2 = afL x bfHi =====
        STAGE_A(2, nxt, kt1); STAGE_A(3, nxt, kt1);
#pragma unroll
        for (int nf = 0; nf < 2; ++nf) {
            const u16* b = cB + brow + (nf + 2) * 1024;
            bfHi[nf][0] = *(const bf16x8*)(b + go0);
            bfHi[nf][1] = *(const bf16x8*)(b + go1);
        }
        RBAR();
        PRIO1(); QUADK(0, 2, afL, bfHi); PRIO0();
        RBAR();

        // ===== P3: stage B.lo(t+2); read afH(8); Q3 = afH x bfLo =====
        STAGE_B(0, cur, kt2); STAGE_B(1, cur, kt2);
#pragma unroll
        for (int mf = 0; mf < 4; ++mf) {
            const u16* b = cA + arow + (mf + 4) * 1024;
            afH[mf][0] = *(const bf16x8*)(b + go0);
            afH[mf][1] = *(const bf16x8*)(b + go1);
        }
        RBAR();
        PRIO1(); QUADK(4, 0, afH, bfLo); PRIO0();
        RBAR();

        // ===== P4: stage B.hi(t+2); GATE; read bfLo(t+1); Q4 = afH x bfHi =====
        STAGE_B(2, cur, kt2); STAGE_B(3, cur, kt2);
        GATE4();                   // retires all of tile t+1; keeps B(t+2)
#pragma unroll
        for (int nf = 0; nf < 2; ++nf) {
            const u16* b = nB + brow + nf * 1024;
            bfLo[nf][0] = *(const bf16x8*)(b + go0);
            bfLo[nf][1] = *(const bf16x8*)(b + go1);
        }
        RBAR();
        PRIO1(); QUADK(4, 2, afH, bfHi); PRIO0();
        RBAR();
    }
    asm volatile("s_waitcnt vmcnt(0)" ::: "memory");   // drain wrapped prefetch

    // ---- epilogue: + bias, store f32 ----
    const int orow = bm + wr*128 + kgrp*4;
    const int ocol = bn + wc*64 + lrow;
#pragma unroll
    for (int n = 0; n < 4; ++n) {
        const int col = ocol + n*16;
        const float bj = bias[col];
#pragma unroll
        for (int m = 0; m < 8; ++m) {
            const int row = orow + m*16;
#pragma unroll
            for (int r = 0; r < 4; ++r)
                out[(long)(row + r) * N + col] = acc[m][n][r] + bj;
        }
    }
}

// ---------------- fallback: T = scale * x @ A^T  (one wave per row) ----------------
__global__ __launch_bounds__(64) void k_lora_T(const float* __restrict__ x,
                                               const float* __restrict__ A,
                                               float* __restrict__ T) {
    const int m = blockIdx.x;
    const int lane = threadIdx.x;
    const float* xr = x + (long)m * DIN;
    float acc[RANK];
#pragma unroll
    for (int r = 0; r < RANK; ++r) acc[r] = 0.f;
    for (int k = lane * 4; k < DIN; k += 64 * 4) {
        f32x4 xv = *(const f32x4*)(xr + k);
#pragma unroll
        for (int r = 0; r < RANK; ++r) {
            f32x4 av = *(const f32x4*)(A + (long)r * DIN + k);
            acc[r] += xv[0] * av[0] + xv[1] * av[1] + xv[2] * av[2] + xv[3] * av[3];
        }
    }
#pragma unroll
    for (int r = 0; r < RANK; ++r)
        for (int off = 32; off > 0; off >>= 1) acc[r] += __shfl_down(acc[r], off);
    if (lane == 0) {
#pragma unroll
        for (int r = 0; r < RANK; ++r) T[(long)m * RANK + r] = acc[r] * LSCALE;
    }
}

// ---------------- fallback GEMM: f32 sources, reg-staged conversion ----------------
__global__ __launch_bounds__(256) void k_gemm_nows(const float* __restrict__ x,
                                                   const float* __restrict__ W,
                                                   const float* __restrict__ bias,
                                                   const float* __restrict__ T,
                                                   const float* __restrict__ lB,
                                                   float* __restrict__ out) {
    constexpr int FBM = 128, FBN = 128, FBK = 32, K = DIN, N = DOUT;
    __shared__ __align__(16) u16 As[FBM * FBK];
    __shared__ __align__(16) u16 Bs[FBN * FBK];

    const int tid = threadIdx.x;
    const int bm = blockIdx.y * FBM;
    const int bn = blockIdx.x * FBN;
    const int lane = tid & 63;
    const int wid  = tid >> 6;
    const int wr = wid >> 1, wc = wid & 1;
    const int lrow = lane & 15;
    const int kgrp = lane >> 4;

    const int c0 = tid, c1 = tid + 256;
    const float* aS0 = x + (long)(bm + (c0 >> 2)) * K + (c0 & 3) * 8;
    const float* aS1 = x + (long)(bm + (c1 >> 2)) * K + (c1 & 3) * 8;
    const float* bS0 = W + (long)(bn + (c0 >> 2)) * K + (c0 & 3) * 8;
    const float* bS1 = W + (long)(bn + (c1 >> 2)) * K + (c1 & 3) * 8;
    u16* aD0 = As + c0 * 8;  u16* aD1 = As + c1 * 8;
    u16* bD0 = Bs + c0 * 8;  u16* bD1 = Bs + c1 * 8;

    const u16* aR = As + (wr * 64 + lrow) * FBK + kgrp * 8;
    const u16* bR = Bs + (wc * 64 + lrow) * FBK + kgrp * 8;

    f32x4 acc[4][4];
#pragma unroll
    for (int i = 0; i < 4; ++i)
#pragma unroll
        for (int j = 0; j < 4; ++j) acc[i][j] = (f32x4){0.f, 0.f, 0.f, 0.f};

    for (int k0 = 0; k0 < K; k0 += FBK) {
        f32x4 a00 = *(const f32x4*)aS0, a01 = *(const f32x4*)(aS0 + 4);
        f32x4 a10 = *(const f32x4*)aS1, a11 = *(const f32x4*)(aS1 + 4);
        f32x4 b00 = *(const f32x4*)bS0, b01 = *(const f32x4*)(bS0 + 4);
        f32x4 b10 = *(const f32x4*)bS1, b11 = *(const f32x4*)(bS1 + 4);
        aS0 += FBK; aS1 += FBK; bS0 += FBK; bS1 += FBK;
        if (k0) __syncthreads();
        *(u16x8*)aD0 = pack8(a00, a01);
        *(u16x8*)aD1 = pack8(a10, a11);
        *(u16x8*)bD0 = pack8(b00, b01);
        *(u16x8*)bD1 = pack8(b10, b11);
        __syncthreads();

        bf16x8 af[4], bf[4];
#pragma unroll
        for (int i = 0; i < 4; ++i) af[i] = *(const bf16x8*)(aR + i * 16 * FBK);
#pragma unroll
        for (int j = 0; j < 4; ++j) bf[j] = *(const bf16x8*)(bR + j * 16 * FBK);
#pragma unroll
        for (int i = 0; i < 4; ++i)
#pragma unroll
            for (int j = 0; j < 4; ++j)
                acc[i][j] = __builtin_amdgcn_mfma_f32_16x16x32_bf16(af[i], bf[j], acc[i][j], 0, 0, 0);
    }

#pragma unroll
    for (int j = 0; j < 4; ++j) {
        const int col = bn + wc * 64 + j * 16 + lrow;
        const float bj = bias[col];
        float bl[RANK];
#pragma unroll
        for (int q = 0; q < RANK; ++q) bl[q] = lB[(long)col * RANK + q];
#pragma unroll
        for (int i = 0; i < 4; ++i) {
            const int row0 = bm + wr * 64 + i * 16 + kgrp * 4;
#pragma unroll
            for (int r = 0; r < 4; ++r) {
                const int row = row0 + r;
                const float* Trow = T + (long)row * RANK;
                float s = bj;
#pragma unroll
                for (int q = 0; q < RANK; ++q) s += Trow[q] * bl[q];
                out[(long)row * N + col] = acc[i][j][r] + s;
            }
        }
    }
}

extern "C" void kernel_launch(void* const* d_in, const int* in_sizes, int n_in,
                              void* d_out, int out_size, void* d_ws, size_t ws_size,
                              hipStream_t stream) {
    const float* x    = (const float*)d_in[0];
    const float* W    = (const float*)d_in[1];
    const float* bias = (const float*)d_in[2];
    const float* lA   = (const float*)d_in[3];
    const float* lB   = (const float*)d_in[4];
    float* out = (float*)d_out;

    const size_t xb_bytes = (size_t)MTOT * DIN * sizeof(u16);   // 64 MiB
    const size_t wb_bytes = (size_t)DOUT * DIN * sizeof(u16);   // 32 MiB

    if (ws_size >= xb_bytes + wb_bytes) {
        u16* xb = (u16*)d_ws;
        u16* wb = (u16*)((char*)d_ws + xb_bytes);
        k_convert_x <<<(int)((long)MTOT * DIN / 8 / 256), 256, 0, stream>>>(x, xb);
        k_build_weff<<<(int)((long)DOUT * DIN / 8 / 256), 256, 0, stream>>>(W, lA, lB, wb);
        k_gemm_ws   <<<(MTOT / BM) * (DOUT / BN), 512, 0, stream>>>(xb, wb, bias, out);
    } else {
        float* T = (float*)d_ws;   // 512 KiB
        k_lora_T   <<<MTOT, 64, 0, stream>>>(x, lA, T);
        k_gemm_nows<<<dim3(DOUT / 128, MTOT / 128), 256, 0, stream>>>(x, W, bias, T, lB, out);
    }
}

// Round 9
// 329.836 us; speedup vs baseline: 1.1590x; 1.0100x over previous
//
#include <hip/hip_runtime.h>
#include <stdint.h>

// ---------------- problem constants (from reference) ----------------
#define DIN   4096
#define DOUT  4096
#define RANK  16
#define MTOT  8192            // 4 * 2048
#define LSCALE 2.0f           // alpha/rank = 32/16

typedef unsigned short u16;
typedef __bf16 bf16x8 __attribute__((ext_vector_type(8)));
typedef float  f32x4  __attribute__((ext_vector_type(4)));
typedef u16    u16x8  __attribute__((ext_vector_type(8)));

__device__ __forceinline__ u16 f2bf(float f) {
    uint32_t u = __builtin_bit_cast(uint32_t, f);
    u = (u + 0x7FFFu + ((u >> 16) & 1u)) >> 16;   // RNE
    return (u16)u;
}

__device__ __forceinline__ u16x8 pack8(f32x4 a, f32x4 b) {
    u16x8 o;
    o[0] = f2bf(a[0]); o[1] = f2bf(a[1]); o[2] = f2bf(a[2]); o[3] = f2bf(a[3]);
    o[4] = f2bf(b[0]); o[5] = f2bf(b[1]); o[6] = f2bf(b[2]); o[7] = f2bf(b[3]);
    return o;
}

#define GLDS16(g, l) __builtin_amdgcn_global_load_lds( \
    (const __attribute__((address_space(1))) void*)(g), \
    (__attribute__((address_space(3))) void*)(l), 16, 0, 0)

// ---------------- pass 1a: x (f32) -> xb (bf16) ----------------
__global__ __launch_bounds__(256) void k_convert_x(const float* __restrict__ x,
                                                   u16* __restrict__ xb) {
    long i = ((long)blockIdx.x * 256 + threadIdx.x) * 8;
    f32x4 a = *(const f32x4*)(x + i);
    f32x4 b = *(const f32x4*)(x + i + 4);
    *(u16x8*)(xb + i) = pack8(a, b);
}

// ---------------- pass 1b: W_eff = W + scale * B @ A  (bf16) ----------------
__global__ __launch_bounds__(256) void k_build_weff(const float* __restrict__ W,
                                                    const float* __restrict__ A,
                                                    const float* __restrict__ B,
                                                    u16* __restrict__ wb) {
    long t = (long)blockIdx.x * 256 + threadIdx.x;
    long i = t * 8;
    int o = (int)(i >> 12);        // / DIN
    int d = (int)(i & (DIN - 1));
    float sB[RANK];
#pragma unroll
    for (int r = 0; r < RANK; ++r) sB[r] = B[o * RANK + r] * LSCALE;
    f32x4 w0 = *(const f32x4*)(W + i);
    f32x4 w1 = *(const f32x4*)(W + i + 4);
#pragma unroll
    for (int r = 0; r < RANK; ++r) {
        f32x4 a0 = *(const f32x4*)(A + (long)r * DIN + d);
        f32x4 a1 = *(const f32x4*)(A + (long)r * DIN + d + 4);
        w0 += a0 * sB[r];
        w1 += a1 * sB[r];
    }
    *(u16x8*)(wb + i) = pack8(w0, w1);
}

// ---------------- main GEMM: out = xb @ wb^T + bias ----------------
// 256x256, BK=64, 8 waves (2Mx4N, wave 128x64). SINGLE barrier per phase,
// placed at phase END: phase = [STAGE; READS; MFMA; ABAR]. The CU matrix
// queue staggers the 8 waves' MFMA clusters; early-finishing waves issue
// next-phase ds_reads while late waves still MFMA -> LDS overlaps matrix
// (the former post-MFMA barrier forced CU-wide LDS/MFMA alternation = the
// measured 609cy/phase = 310 MFMA + 250 LDS + barrier).
//   P1: stage A.lo(t+1); read afL(8);  Q1=afL*bfLo;  BAR
//   P2: stage A.hi(t+1); read bfHi(4); Q2=afL*bfHi;  BAR
//   P3: stage B.lo(t+2); read afH(8);  Q3=afH*bfLo;  BAR
//   P4: stage B.hi(t+2); GATE vmcnt(4); read bfLo(t+1)(4); Q4=afH*bfHi; BAR
// Skew bound = 1 phase (one barrier/phase). All stage targets are >=2
// barriers past their region's last read; all reads >=3 phases (~1800cy >
// 900cy HBM) past producer issue. vmcnt never 0 in loop.
#define BM 256
#define BN 256
#define BK 64
#define NT (DIN / BK)          // 64 K-tiles

#define MFMA16(d, a, b) d = __builtin_amdgcn_mfma_f32_16x16x32_bf16(a, b, d, 0, 0, 0)
#define ABAR()   asm volatile("s_barrier" ::: "memory")
#define GATE4()  asm volatile("s_waitcnt vmcnt(4)" ::: "memory")
#define PRIO1()  __builtin_amdgcn_s_setprio(1)
#define PRIO0()  __builtin_amdgcn_s_setprio(0)

// 16 MFMAs, kk-outer (8 independent accs between dependent reuses)
#define QUADK(mo, no, AF, BF) \
    _Pragma("unroll") \
    for (int kk = 0; kk < 2; ++kk) { \
        _Pragma("unroll") \
        for (int m = 0; m < 4; ++m) { \
            _Pragma("unroll") \
            for (int n = 0; n < 2; ++n) { \
                MFMA16(acc[(mo)+m][(no)+n], AF[m][kk], BF[n][kk]); \
            } \
        } \
    }

__global__ __launch_bounds__(512, 2) void k_gemm_ws(const u16* __restrict__ xb,
                                                    const u16* __restrict__ wb,
                                                    const float* __restrict__ bias,
                                                    float* __restrict__ out) {
    constexpr int K = DIN, N = DOUT;
    __shared__ alignas(16) u16 lds[65536];   // A0@0 A1@16384 B0@32768 B1@49152 (u16)

    // T1: bijective XCD swizzle (gridDim.x = 512, divisible by 8)
    const int nchunk = gridDim.x >> 3;
    const int bid = blockIdx.x;
    const int wg  = (bid & 7) * nchunk + (bid >> 3);
    const int bm  = (wg & 31) * BM;
    const int bn  = (wg >> 5) * BN;

    const int tid  = threadIdx.x;
    const int lane = tid & 63;
    const int wid  = tid >> 6;         // 0..7
    const int wr   = wid >> 2;         // 0..1 -> rows wr*128..+127
    const int wc   = wid & 3;          // 0..3 -> cols wc*64..+63
    const int lrow = lane & 15;
    const int kgrp = lane >> 4;        // 0..3

    // ---- staging geometry (T2: pre-swizzled global source, linear LDS dest) ----
    const int srow = tid >> 3;                       // 0..63
    const int sgl  = (tid & 7) ^ (srow & 7);
    const u16* const aSrcB = xb + (long)(bm + srow) * K + sgl * 8;
    const u16* const bSrcB = wb + (long)(bn + srow) * K + sgl * 8;

    // chunk c = tile rows 64c..64c+63. lo = c0,c1; hi = c2,c3.
#define STAGE_A(c, buf, kt) GLDS16(aSrcB + (long)(64*(c))*K + (kt)*BK, \
                                   lds + (buf)*16384 + (c)*4096 + tid*8)
#define STAGE_B(c, buf, kt) GLDS16(bSrcB + (long)(64*(c))*K + (kt)*BK, \
                                   lds + 32768 + (buf)*16384 + (c)*4096 + tid*8)

    // ---- fragment-read geometry (swizzled) ----
    const int go0 = (kgrp ^ (lrow & 7)) * 8;   // kk=0 granule (u16 units)
    const int go1 = go0 ^ 32;                  // kk=1 (granule ^ 4)
    const int arow = (wr*128 + lrow) * 64;     // wave A base row offset
    const int brow = (wc*64  + lrow) * 64;     // wave B base row offset

    f32x4 acc[8][4];
#pragma unroll
    for (int m = 0; m < 8; ++m)
#pragma unroll
        for (int n = 0; n < 4; ++n) acc[m][n] = (f32x4){0.f, 0.f, 0.f, 0.f};

    bf16x8 afL[4][2], afH[4][2], bfLo[2][2], bfHi[2][2];

    // ---- prologue: tile0 -> buf0, B(1) -> buf1; counted gate; read bfLo(0) ----
    STAGE_A(0, 0, 0); STAGE_A(1, 0, 0);
    STAGE_A(2, 0, 0); STAGE_A(3, 0, 0);
    STAGE_B(0, 0, 0); STAGE_B(1, 0, 0);
    STAGE_B(2, 0, 0); STAGE_B(3, 0, 0);
    STAGE_B(0, 1, 1); STAGE_B(1, 1, 1);
    STAGE_B(2, 1, 1); STAGE_B(3, 1, 1);
    GATE4();                       // retires tile0's 8; keeps B(1) in flight
    __syncthreads();
#pragma unroll
    for (int nf = 0; nf < 2; ++nf) {
        const u16* b = lds + 32768 + brow + nf * 1024;
        bfLo[nf][0] = *(const bf16x8*)(b + go0);
        bfLo[nf][1] = *(const bf16x8*)(b + go1);
    }

    for (int t = 0; t < NT; ++t) {
        const int cur = t & 1, nxt = cur ^ 1;
        const int kt1 = (t + 1) & (NT - 1);
        const int kt2 = (t + 2) & (NT - 1);
        const u16* const cA = lds + cur * 16384;
        const u16* const cB = lds + 32768 + cur * 16384;
        const u16* const nB = lds + 32768 + nxt * 16384;

        // ===== P1: stage A.lo(t+1); read afL(8); Q1 = afL x bfLo; BAR =====
        STAGE_A(0, nxt, kt1); STAGE_A(1, nxt, kt1);
#pragma unroll
        for (int mf = 0; mf < 4; ++mf) {
            const u16* b = cA + arow + mf * 1024;
            afL[mf][0] = *(const bf16x8*)(b + go0);
            afL[mf][1] = *(const bf16x8*)(b + go1);
        }
        PRIO1(); QUADK(0, 0, afL, bfLo); PRIO0();
        ABAR();

        // ===== P2: stage A.hi(t+1); read bfHi(4); Q2 = afL x bfHi; BAR =====
        STAGE_A(2, nxt, kt1); STAGE_A(3, nxt, kt1);
#pragma unroll
        for (int nf = 0; nf < 2; ++nf) {
            const u16* b = cB + brow + (nf + 2) * 1024;
            bfHi[nf][0] = *(const bf16x8*)(b + go0);
            bfHi[nf][1] = *(const bf16x8*)(b + go1);
        }
        PRIO1(); QUADK(0, 2, afL, bfHi); PRIO0();
        ABAR();

        // ===== P3: stage B.lo(t+2); read afH(8); Q3 = afH x bfLo; BAR =====
        STAGE_B(0, cur, kt2); STAGE_B(1, cur, kt2);
#pragma unroll
        for (int mf = 0; mf < 4; ++mf) {
            const u16* b = cA + arow + (mf + 4) * 1024;
            afH[mf][0] = *(const bf16x8*)(b + go0);
            afH[mf][1] = *(const bf16x8*)(b + go1);
        }
        PRIO1(); QUADK(4, 0, afH, bfLo); PRIO0();
        ABAR();

        // ===== P4: stage B.hi(t+2); GATE; read bfLo(t+1); Q4 = afH x bfHi; BAR =====
        STAGE_B(2, cur, kt2); STAGE_B(3, cur, kt2);
        GATE4();                   // retires all of tile t+1; keeps B(t+2)
#pragma unroll
        for (int nf = 0; nf < 2; ++nf) {
            const u16* b = nB + brow + nf * 1024;
            bfLo[nf][0] = *(const bf16x8*)(b + go0);
            bfLo[nf][1] = *(const bf16x8*)(b + go1);
        }
        PRIO1(); QUADK(4, 2, afH, bfHi); PRIO0();
        ABAR();
    }
    asm volatile("s_waitcnt vmcnt(0)" ::: "memory");   // drain wrapped prefetch

    // ---- epilogue: + bias, store f32 ----
    const int orow = bm + wr*128 + kgrp*4;
    const int ocol = bn + wc*64 + lrow;
#pragma unroll
    for (int n = 0; n < 4; ++n) {
        const int col = ocol + n*16;
        const float bj = bias[col];
#pragma unroll
        for (int m = 0; m < 8; ++m) {
            const int row = orow + m*16;
#pragma unroll
            for (int r = 0; r < 4; ++r)
                out[(long)(row + r) * N + col] = acc[m][n][r] + bj;
        }
    }
}

// ---------------- fallback: T = scale * x @ A^T  (one wave per row) ----------------
__global__ __launch_bounds__(64) void k_lora_T(const float* __restrict__ x,
                                               const float* __restrict__ A,
                                               float* __restrict__ T) {
    const int m = blockIdx.x;
    const int lane = threadIdx.x;
    const float* xr = x + (long)m * DIN;
    float acc[RANK];
#pragma unroll
    for (int r = 0; r < RANK; ++r) acc[r] = 0.f;
    for (int k = lane * 4; k < DIN; k += 64 * 4) {
        f32x4 xv = *(const f32x4*)(xr + k);
#pragma unroll
        for (int r = 0; r < RANK; ++r) {
            f32x4 av = *(const f32x4*)(A + (long)r * DIN + k);
            acc[r] += xv[0] * av[0] + xv[1] * av[1] + xv[2] * av[2] + xv[3] * av[3];
        }
    }
#pragma unroll
    for (int r = 0; r < RANK; ++r)
        for (int off = 32; off > 0; off >>= 1) acc[r] += __shfl_down(acc[r], off);
    if (lane == 0) {
#pragma unroll
        for (int r = 0; r < RANK; ++r) T[(long)m * RANK + r] = acc[r] * LSCALE;
    }
}

// ---------------- fallback GEMM: f32 sources, reg-staged conversion ----------------
__global__ __launch_bounds__(256) void k_gemm_nows(const float* __restrict__ x,
                                                   const float* __restrict__ W,
                                                   const float* __restrict__ bias,
                                                   const float* __restrict__ T,
                                                   const float* __restrict__ lB,
                                                   float* __restrict__ out) {
    constexpr int FBM = 128, FBN = 128, FBK = 32, K = DIN, N = DOUT;
    __shared__ __align__(16) u16 As[FBM * FBK];
    __shared__ __align__(16) u16 Bs[FBN * FBK];

    const int tid = threadIdx.x;
    const int bm = blockIdx.y * FBM;
    const int bn = blockIdx.x * FBN;
    const int lane = tid & 63;
    const int wid  = tid >> 6;
    const int wr = wid >> 1, wc = wid & 1;
    const int lrow = lane & 15;
    const int kgrp = lane >> 4;

    const int c0 = tid, c1 = tid + 256;
    const float* aS0 = x + (long)(bm + (c0 >> 2)) * K + (c0 & 3) * 8;
    const float* aS1 = x + (long)(bm + (c1 >> 2)) * K + (c1 & 3) * 8;
    const float* bS0 = W + (long)(bn + (c0 >> 2)) * K + (c0 & 3) * 8;
    const float* bS1 = W + (long)(bn + (c1 >> 2)) * K + (c1 & 3) * 8;
    u16* aD0 = As + c0 * 8;  u16* aD1 = As + c1 * 8;
    u16* bD0 = Bs + c0 * 8;  u16* bD1 = Bs + c1 * 8;

    const u16* aR = As + (wr * 64 + lrow) * FBK + kgrp * 8;
    const u16* bR = Bs + (wc * 64 + lrow) * FBK + kgrp * 8;

    f32x4 acc[4][4];
#pragma unroll
    for (int i = 0; i < 4; ++i)
#pragma unroll
        for (int j = 0; j < 4; ++j) acc[i][j] = (f32x4){0.f, 0.f, 0.f, 0.f};

    for (int k0 = 0; k0 < K; k0 += FBK) {
        f32x4 a00 = *(const f32x4*)aS0, a01 = *(const f32x4*)(aS0 + 4);
        f32x4 a10 = *(const f32x4*)aS1, a11 = *(const f32x4*)(aS1 + 4);
        f32x4 b00 = *(const f32x4*)bS0, b01 = *(const f32x4*)(bS0 + 4);
        f32x4 b10 = *(const f32x4*)bS1, b11 = *(const f32x4*)(bS1 + 4);
        aS0 += FBK; aS1 += FBK; bS0 += FBK; bS1 += FBK;
        if (k0) __syncthreads();
        *(u16x8*)aD0 = pack8(a00, a01);
        *(u16x8*)aD1 = pack8(a10, a11);
        *(u16x8*)bD0 = pack8(b00, b01);
        *(u16x8*)bD1 = pack8(b10, b11);
        __syncthreads();

        bf16x8 af[4], bf[4];
#pragma unroll
        for (int i = 0; i < 4; ++i) af[i] = *(const bf16x8*)(aR + i * 16 * FBK);
#pragma unroll
        for (int j = 0; j < 4; ++j) bf[j] = *(const bf16x8*)(bR + j * 16 * FBK);
#pragma unroll
        for (int i = 0; i < 4; ++i)
#pragma unroll
            for (int j = 0; j < 4; ++j)
                acc[i][j] = __builtin_amdgcn_mfma_f32_16x16x32_bf16(af[i], bf[j], acc[i][j], 0, 0, 0);
    }

#pragma unroll
    for (int j = 0; j < 4; ++j) {
        const int col = bn + wc * 64 + j * 16 + lrow;
        const float bj = bias[col];
        float bl[RANK];
#pragma unroll
        for (int q = 0; q < RANK; ++q) bl[q] = lB[(long)col * RANK + q];
#pragma unroll
        for (int i = 0; i < 4; ++i) {
            const int row0 = bm + wr * 64 + i * 16 + kgrp * 4;
#pragma unroll
            for (int r = 0; r < 4; ++r) {
                const int row = row0 + r;
                const float* Trow = T + (long)row * RANK;
                float s = bj;
#pragma unroll
                for (int q = 0; q < RANK; ++q) s += Trow[q] * bl[q];
                out[(long)row * N + col] = acc[i][j][r] + s;
            }
        }
    }
}

extern "C" void kernel_launch(void* const* d_in, const int* in_sizes, int n_in,
                              void* d_out, int out_size, void* d_ws, size_t ws_size,
                              hipStream_t stream) {
    const float* x    = (const float*)d_in[0];
    const float* W    = (const float*)d_in[1];
    const float* bias = (const float*)d_in[2];
    const float* lA   = (const float*)d_in[3];
    const float* lB   = (const float*)d_in[4];
    float* out = (float*)d_out;

    const size_t xb_bytes = (size_t)MTOT * DIN * sizeof(u16);   // 64 MiB
    const size_t wb_bytes = (size_t)DOUT * DIN * sizeof(u16);   // 32 MiB

    if (ws_size >= xb_bytes + wb_bytes) {
        u16* xb = (u16*)d_ws;
        u16* wb = (u16*)((char*)d_ws + xb_bytes);
        k_convert_x <<<(int)((long)MTOT * DIN / 8 / 256), 256, 0, stream>>>(x, xb);
        k_build_weff<<<(int)((long)DOUT * DIN / 8 / 256), 256, 0, stream>>>(W, lA, lB, wb);
        k_gemm_ws   <<<(MTOT / BM) * (DOUT / BN), 512, 0, stream>>>(xb, wb, bias, out);
    } else {
        float* T = (float*)d_ws;   // 512 KiB
        k_lora_T   <<<MTOT, 64, 0, stream>>>(x, lA, T);
        k_gemm_nows<<<dim3(DOUT / 128, MTOT / 128), 256, 0, stream>>>(x, W, bias, T, lB, out);
    }
}